// Round 3
// baseline (604.222 us; speedup 1.0000x reference)
//
#include <hip/hip_runtime.h>
#include <hip/hip_bf16.h>

typedef __attribute__((ext_vector_type(8))) short short8;
typedef __attribute__((ext_vector_type(4))) float floatx4;

#define SCALE_Q 0.17677669529663687f

__device__ __forceinline__ short f2bf(float f) {
  union { float f; unsigned u; } a; a.f = f;
  unsigned r = (a.u + 0x7FFFu + ((a.u >> 16) & 1u)) >> 16;
  return (short)r;
}

// window-order row -> spatial row index (reverse shift +3 roll), per reference
__device__ __forceinline__ int spatial_row(int r) {
  int n = r / 49, tw = r - n * 49;
  int bb = n >> 6, wdx = n & 63;
  int rh = (wdx >> 3) * 7 + tw / 7, rw = (wdx & 7) * 7 + tw % 7;
  int oh = rh + 3; if (oh >= 56) oh -= 56;
  int ow = rw + 3; if (ow >= 56) ow -= 56;
  return bb * 3136 + oh * 56 + ow;
}

// ---------- weight transpose + bf16: dst[n*K+k] = src[k*N+n] ----------
__global__ void transpose_w_k(const float* __restrict__ src, short* __restrict__ dst,
                              int K, int N) {
  int i = blockIdx.x * 256 + threadIdx.x;
  if (i >= N * K) return;
  int n = i / K, k = i - n * K;
  dst[i] = f2bf(src[(size_t)k * N + n]);
}

// ---------- fused pos_bias + shifted-window mask table: bm[w][h][49][49] ----------
__global__ void prep_bm_k(const float* __restrict__ pos_bias, float* __restrict__ bm) {
  int i = blockIdx.x * 256 + threadIdx.x;
  if (i >= 64 * 6 * 49 * 49) return;
  int j = i % 49; int t = i / 49; int ii = t % 49; t /= 49; int h = t % 6; int w = t / 6;
  int ih = ii / 7, iw = ii - ih * 7, jh = j / 7, jw = j - jh * 7;
  int rel = (ih - jh + 6) * 13 + (iw - jw + 6);
  float v = pos_bias[rel * 6 + h];
  int wh = w >> 3, ww = w & 7;
  int ri = wh * 7 + ih, ci = ww * 7 + iw, rj = wh * 7 + jh, cj = ww * 7 + jw;
  int regi = ((ri >= 49) + (ri >= 53)) * 3 + ((ci >= 49) + (ci >= 53));
  int regj = ((rj >= 49) + (rj >= 53)) * 3 + ((cj >= 49) + (cj >= 53));
  if (regi != regj) v -= 100.0f;
  bm[i] = v;
}

// ---------- LN1 + cyclic shift + window partition (one wave per row) ----------
__global__ __launch_bounds__(256) void ln_k(const float* __restrict__ x,
    const float* __restrict__ g, const float* __restrict__ bta,
    short* __restrict__ outb) {
  int wid = threadIdx.x >> 6, lane = threadIdx.x & 63;
  int r = blockIdx.x * 4 + wid;
  int n = r / 49, tw = r - n * 49;
  int bb = n >> 6, wdx = n & 63;
  int rh = (wdx >> 3) * 7 + tw / 7, rw = (wdx & 7) * 7 + tw % 7;
  int sh = rh + 3; if (sh >= 56) sh -= 56;
  int sw = rw + 3; if (sw >= 56) sw -= 56;
  size_t src = ((size_t)bb * 3136 + sh * 56 + sw) * 192;
  const float* xr = x + src;
  float v0 = xr[lane], v1 = xr[lane + 64], v2 = xr[lane + 128];
  float s = v0 + v1 + v2, sq = v0 * v0 + v1 * v1 + v2 * v2;
  #pragma unroll
  for (int o = 32; o >= 1; o >>= 1) { s += __shfl_xor(s, o); sq += __shfl_xor(sq, o); }
  float mean = s * (1.0f / 192.0f);
  float rstd = rsqrtf(sq * (1.0f / 192.0f) - mean * mean + 1e-5f);
  short* orow = outb + (size_t)r * 192;
  orow[lane]       = f2bf((v0 - mean) * rstd * g[lane]       + bta[lane]);
  orow[lane + 64]  = f2bf((v1 - mean) * rstd * g[lane + 64]  + bta[lane + 64]);
  orow[lane + 128] = f2bf((v2 - mean) * rstd * g[lane + 128] + bta[lane + 128]);
}

// ---------- QKV GEMM (128x64 tile, 4 waves) with head-scatter epilogue ----------
__global__ __launch_bounds__(256) void gemm_qkv_k(
    const short* __restrict__ A, const short* __restrict__ Bt,
    const float* __restrict__ bias, short* __restrict__ outp, int N, int K) {
  __shared__ short As[128][72];
  __shared__ short Bs[64][72];
  int tid = threadIdx.x;
  int gmb = blockIdx.y * 128;
  int gnb = blockIdx.x * 64;
  int wid = tid >> 6, lane = tid & 63;
  int wm = wid >> 1, wn = wid & 1;
  int lr = lane & 15, lk = (lane >> 4) << 3, lq = (lane >> 4) << 2;
  floatx4 acc[4][2];
  #pragma unroll
  for (int i = 0; i < 4; ++i)
    #pragma unroll
    for (int j = 0; j < 2; ++j) acc[i][j] = (floatx4)(0.0f);

  for (int k0 = 0; k0 < K; k0 += 64) {
    #pragma unroll
    for (int i = 0; i < 4; ++i) {
      int u = tid + 256 * i;
      int row = u >> 3, cb = (u & 7) << 3;
      *(short8*)&As[row][cb] = *(const short8*)&A[(size_t)(gmb + row) * K + k0 + cb];
    }
    #pragma unroll
    for (int i = 0; i < 2; ++i) {
      int u = tid + 256 * i;
      int row = u >> 3, cb = (u & 7) << 3;
      *(short8*)&Bs[row][cb] = *(const short8*)&Bt[(size_t)(gnb + row) * K + k0 + cb];
    }
    __syncthreads();
    #pragma unroll
    for (int kk = 0; kk < 64; kk += 32) {
      short8 af[4], bfr[2];
      #pragma unroll
      for (int mi = 0; mi < 4; ++mi)
        af[mi] = *(const short8*)&As[wm * 64 + mi * 16 + lr][kk + lk];
      #pragma unroll
      for (int ni = 0; ni < 2; ++ni)
        bfr[ni] = *(const short8*)&Bs[wn * 32 + ni * 16 + lr][kk + lk];
      #pragma unroll
      for (int mi = 0; mi < 4; ++mi)
        #pragma unroll
        for (int ni = 0; ni < 2; ++ni)
          acc[mi][ni] = __builtin_amdgcn_mfma_f32_16x16x32_bf16(af[mi], bfr[ni], acc[mi][ni], 0, 0, 0);
    }
    __syncthreads();
  }

  #pragma unroll
  for (int mi = 0; mi < 4; ++mi)
    #pragma unroll
    for (int ni = 0; ni < 2; ++ni)
      #pragma unroll
      for (int r = 0; r < 4; ++r) {
        int grow = gmb + wm * 64 + mi * 16 + lq + r;
        int gcol = gnb + wn * 32 + ni * 16 + lr;
        float v = acc[mi][ni][r] + bias[gcol];
        int which = gcol / 192, rem = gcol - which * 192;
        if (which == 0) v *= SCALE_Q;
        int head = rem >> 5, d = rem & 31;
        int n = grow / 49, tw = grow - n * 49;
        outp[((((size_t)(n * 6 + head) * 3 + which) * 49 + tw) << 5) + d] = f2bf(v);
      }
}

// ---------- window attention core: 1 wave per (window, head), NO softmax ----------
__global__ __launch_bounds__(256) void attn_k(const short* __restrict__ qkv,
    const float* __restrict__ bm, short* __restrict__ obuf) {
  __shared__ short lds[4][6912];
  int wid = threadIdx.x >> 6, lane = threadIdx.x & 63;
  int pair = blockIdx.x * 4 + wid;
  int n = pair / 6, h = pair - n * 6;
  short* Vt = &lds[wid][0];
  short* Ps = &lds[wid][32 * 72];
  const short* Qb = qkv + (size_t)((n * 6 + h) * 3) * 1568;
  const short* Kb = Qb + 1568;
  const short* Vb = Qb + 3136;
  int lr = lane & 15, lk = (lane >> 4) << 3, lq = (lane >> 4) << 2;

  #pragma unroll
  for (int it = 0; it < 8; ++it) {
    int u = lane + 64 * it;
    Vt[(u >> 4) * 72 + 48 + (u & 15)] = 0;
  }
  #pragma unroll
  for (int it = 0; it < 4; ++it) {
    int u = lane + 64 * it;
    if (u < 196) {
      int tw = u >> 2, db = (u & 3) << 3;
      short8 vv = *(const short8*)&Vb[tw * 32 + db];
      #pragma unroll
      for (int j = 0; j < 8; ++j) Vt[(db + j) * 72 + tw] = vv[j];
    }
  }

  short8 qf[4], kf[4];
  #pragma unroll
  for (int mi = 0; mi < 4; ++mi)
    qf[mi] = *(const short8*)&Qb[(mi * 16 + lr) * 32 + lk];
  #pragma unroll
  for (int nj = 0; nj < 4; ++nj)
    kf[nj] = *(const short8*)&Kb[(nj * 16 + lr) * 32 + lk];
  floatx4 s[4][4];
  #pragma unroll
  for (int mi = 0; mi < 4; ++mi)
    #pragma unroll
    for (int nj = 0; nj < 4; ++nj)
      s[mi][nj] = __builtin_amdgcn_mfma_f32_16x16x32_bf16(qf[mi], kf[nj], (floatx4)(0.0f), 0, 0, 0);

  const float* bmw = bm + (size_t)((n & 63) * 6 + h) * 2401;
  #pragma unroll
  for (int mi = 0; mi < 4; ++mi)
    #pragma unroll
    for (int nj = 0; nj < 4; ++nj)
      #pragma unroll
      for (int r = 0; r < 4; ++r) {
        int i = mi * 16 + lq + r;
        int j = nj * 16 + lr;
        float v = 0.0f;
        if (i < 49 && j < 49) v = s[mi][nj][r] + bmw[i * 49 + j];
        Ps[i * 72 + j] = f2bf(v);
      }

  floatx4 o[4][2];
  #pragma unroll
  for (int mi = 0; mi < 4; ++mi)
    #pragma unroll
    for (int ni = 0; ni < 2; ++ni) o[mi][ni] = (floatx4)(0.0f);
  #pragma unroll
  for (int kc = 0; kc < 2; ++kc) {
    short8 pf[4], vf[2];
    #pragma unroll
    for (int mi = 0; mi < 4; ++mi)
      pf[mi] = *(const short8*)&Ps[(mi * 16 + lr) * 72 + kc * 32 + lk];
    #pragma unroll
    for (int ni = 0; ni < 2; ++ni)
      vf[ni] = *(const short8*)&Vt[(ni * 16 + lr) * 72 + kc * 32 + lk];
    #pragma unroll
    for (int mi = 0; mi < 4; ++mi)
      #pragma unroll
      for (int ni = 0; ni < 2; ++ni)
        o[mi][ni] = __builtin_amdgcn_mfma_f32_16x16x32_bf16(pf[mi], vf[ni], o[mi][ni], 0, 0, 0);
  }
  #pragma unroll
  for (int mi = 0; mi < 4; ++mi)
    #pragma unroll
    for (int ni = 0; ni < 2; ++ni)
      #pragma unroll
      for (int r = 0; r < 4; ++r) {
        int i = mi * 16 + lq + r;
        if (i < 49)
          obuf[((size_t)n * 49 + i) * 192 + h * 32 + ni * 16 + lr] = f2bf(o[mi][ni][r]);
      }
}

// ---------- proj + residual + LN2 (64 rows/block, 4 waves, tiny LDS) ----------
// writes x1 (f32, spatial order, into d_out) and ln2 output (bf16, spatial order)
__global__ __launch_bounds__(256, 4) void proj_ln2_k(
    const short* __restrict__ obuf, const short* __restrict__ projT,
    const float* __restrict__ proj_b, const float* __restrict__ x,
    const float* __restrict__ g2, const float* __restrict__ bt2,
    float* __restrict__ x1out, short* __restrict__ ln2out) {
  __shared__ float sums[64][2][2];
  __shared__ float stats[64][2];
  int tid = threadIdx.x;
  int wid = tid >> 6, lane = tid & 63;
  int wm = wid >> 1, wn = wid & 1;
  int lr = lane & 15, lk = (lane >> 4) << 3, lq = (lane >> 4) << 2;
  int R0 = blockIdx.x * 64;

  floatx4 acc[2][6];
  #pragma unroll
  for (int mi = 0; mi < 2; ++mi)
    #pragma unroll
    for (int ni = 0; ni < 6; ++ni) acc[mi][ni] = (floatx4)(0.0f);

  #pragma unroll
  for (int kk = 0; kk < 6; ++kk) {
    short8 af[2], bfr[6];
    #pragma unroll
    for (int mi = 0; mi < 2; ++mi)
      af[mi] = *(const short8*)&obuf[(size_t)(R0 + wm * 32 + mi * 16 + lr) * 192 + kk * 32 + lk];
    #pragma unroll
    for (int ni = 0; ni < 6; ++ni)
      bfr[ni] = *(const short8*)&projT[(size_t)(wn * 96 + ni * 16 + lr) * 192 + kk * 32 + lk];
    #pragma unroll
    for (int mi = 0; mi < 2; ++mi)
      #pragma unroll
      for (int ni = 0; ni < 6; ++ni)
        acc[mi][ni] = __builtin_amdgcn_mfma_f32_16x16x32_bf16(af[mi], bfr[ni], acc[mi][ni], 0, 0, 0);
  }

  int col[6]; float pb[6], gv[6], bv[6];
  #pragma unroll
  for (int ni = 0; ni < 6; ++ni) {
    col[ni] = wn * 96 + ni * 16 + lr;
    pb[ni] = proj_b[col[ni]];
    gv[ni] = g2[col[ni]];
    bv[ni] = bt2[col[ni]];
  }

  int srw[2][4];
  #pragma unroll
  for (int mi = 0; mi < 2; ++mi)
    #pragma unroll
    for (int rr = 0; rr < 4; ++rr) {
      int row_l = wm * 32 + mi * 16 + lq + rr;
      int sr = spatial_row(R0 + row_l);
      srw[mi][rr] = sr;
      float s = 0.0f, sq = 0.0f;
      #pragma unroll
      for (int ni = 0; ni < 6; ++ni) {
        float v = acc[mi][ni][rr] + pb[ni] + x[(size_t)sr * 192 + col[ni]];
        acc[mi][ni][rr] = v;
        s += v; sq += v * v;
      }
      #pragma unroll
      for (int o = 8; o >= 1; o >>= 1) { s += __shfl_xor(s, o); sq += __shfl_xor(sq, o); }
      if (lr == 0) { sums[row_l][wn][0] = s; sums[row_l][wn][1] = sq; }
    }
  __syncthreads();
  if (tid < 64) {
    float s = sums[tid][0][0] + sums[tid][1][0];
    float sq = sums[tid][0][1] + sums[tid][1][1];
    float mean = s * (1.0f / 192.0f);
    float var = sq * (1.0f / 192.0f) - mean * mean;
    stats[tid][0] = mean;
    stats[tid][1] = rsqrtf(var + 1e-5f);
  }
  __syncthreads();

  #pragma unroll
  for (int mi = 0; mi < 2; ++mi)
    #pragma unroll
    for (int rr = 0; rr < 4; ++rr) {
      int row_l = wm * 32 + mi * 16 + lq + rr;
      int sr = srw[mi][rr];
      float mean = stats[row_l][0], rstd = stats[row_l][1];
      #pragma unroll
      for (int ni = 0; ni < 6; ++ni) {
        float v = acc[mi][ni][rr];
        x1out[(size_t)sr * 192 + col[ni]] = v;
        ln2out[(size_t)sr * 192 + col[ni]] = f2bf((v - mean) * rstd * gv[ni] + bv[ni]);
      }
    }
}

// ---------- fused MLP: ln2out -> MLP1+gelu -> MLP2 -> out = x1 + m ----------
// 64 rows/block, 4 waves (wm2 x wn2), As staged once, hidden in 12 LDS chunks.
__global__ __launch_bounds__(256, 4) void mlp_k(
    const short* __restrict__ ln2b, const float* __restrict__ x1,
    const short* __restrict__ w1T, const float* __restrict__ b1,
    const short* __restrict__ w2T, const float* __restrict__ b2,
    float* __restrict__ out) {
  __shared__ short As[64][200];
  __shared__ short Hc[64][72];
  int tid = threadIdx.x;
  int wid = tid >> 6, lane = tid & 63;
  int wm = wid >> 1, wn = wid & 1;
  int lr = lane & 15, lk = (lane >> 4) << 3, lq = (lane >> 4) << 2;
  int R0 = blockIdx.x * 64;

  // stage ln2 tile (64 x 192 bf16), fully coalesced
  #pragma unroll
  for (int it = 0; it < 6; ++it) {
    int u = tid + 256 * it;
    int row = u / 24, cb = (u - row * 24) * 8;
    *(short8*)&As[row][cb] = *(const short8*)&ln2b[(size_t)(R0 + row) * 192 + cb];
  }

  float b2v[6];
  int col[6];
  #pragma unroll
  for (int ni = 0; ni < 6; ++ni) {
    col[ni] = wn * 96 + ni * 16 + lr;
    b2v[ni] = b2[col[ni]];
  }

  floatx4 acc[2][6];
  #pragma unroll
  for (int mi = 0; mi < 2; ++mi)
    #pragma unroll
    for (int ni = 0; ni < 6; ++ni) acc[mi][ni] = (floatx4)(0.0f);
  __syncthreads();

  for (int c = 0; c < 12; ++c) {
    // MLP1: hidden cols [c*64 + wn*32 + si*16 + lr], rows wm*32..
    floatx4 hacc[2][2];
    #pragma unroll
    for (int mi = 0; mi < 2; ++mi)
      #pragma unroll
      for (int si = 0; si < 2; ++si) hacc[mi][si] = (floatx4)(0.0f);
    #pragma unroll
    for (int kk = 0; kk < 6; ++kk) {
      short8 af[2], bf1[2];
      #pragma unroll
      for (int mi = 0; mi < 2; ++mi)
        af[mi] = *(const short8*)&As[wm * 32 + mi * 16 + lr][kk * 32 + lk];
      #pragma unroll
      for (int si = 0; si < 2; ++si)
        bf1[si] = *(const short8*)&w1T[(size_t)(c * 64 + wn * 32 + si * 16 + lr) * 192 + kk * 32 + lk];
      #pragma unroll
      for (int mi = 0; mi < 2; ++mi)
        #pragma unroll
        for (int si = 0; si < 2; ++si)
          hacc[mi][si] = __builtin_amdgcn_mfma_f32_16x16x32_bf16(af[mi], bf1[si], hacc[mi][si], 0, 0, 0);
    }
    #pragma unroll
    for (int si = 0; si < 2; ++si) {
      float b1v = b1[c * 64 + wn * 32 + si * 16 + lr];
      #pragma unroll
      for (int mi = 0; mi < 2; ++mi)
        #pragma unroll
        for (int rr = 0; rr < 4; ++rr) {
          float hv = hacc[mi][si][rr] + b1v;
          float ge = 0.5f * hv * (1.0f + erff(hv * 0.70710678118f));
          Hc[wm * 32 + mi * 16 + lq + rr][wn * 32 + si * 16 + lr] = f2bf(ge);
        }
    }
    __syncthreads();
    // MLP2: acc += Hc x w2T_chunk
    #pragma unroll
    for (int kk = 0; kk < 2; ++kk) {
      short8 ah[2], bf2[6];
      #pragma unroll
      for (int mi = 0; mi < 2; ++mi)
        ah[mi] = *(const short8*)&Hc[wm * 32 + mi * 16 + lr][kk * 32 + lk];
      #pragma unroll
      for (int ni = 0; ni < 6; ++ni)
        bf2[ni] = *(const short8*)&w2T[(size_t)col[ni] * 768 + c * 64 + kk * 32 + lk];
      #pragma unroll
      for (int mi = 0; mi < 2; ++mi)
        #pragma unroll
        for (int ni = 0; ni < 6; ++ni)
          acc[mi][ni] = __builtin_amdgcn_mfma_f32_16x16x32_bf16(ah[mi], bf2[ni], acc[mi][ni], 0, 0, 0);
    }
    __syncthreads();
  }

  // out = x1 + m + b2 (all linear in spatial order)
  #pragma unroll
  for (int mi = 0; mi < 2; ++mi)
    #pragma unroll
    for (int rr = 0; rr < 4; ++rr) {
      size_t r = (size_t)(R0 + wm * 32 + mi * 16 + lq + rr) * 192;
      #pragma unroll
      for (int ni = 0; ni < 6; ++ni)
        out[r + col[ni]] = x1[r + col[ni]] + acc[mi][ni][rr] + b2v[ni];
    }
}

extern "C" void kernel_launch(void* const* d_in, const int* in_sizes, int n_in,
                              void* d_out, int out_size, void* d_ws, size_t ws_size,
                              hipStream_t stream) {
  const float* x      = (const float*)d_in[0];
  const float* ln1_g  = (const float*)d_in[1];
  const float* ln1_b  = (const float*)d_in[2];
  const float* qkv_w  = (const float*)d_in[3];
  const float* qkv_b  = (const float*)d_in[4];
  const float* pos_b  = (const float*)d_in[5];
  const float* proj_w = (const float*)d_in[6];
  const float* proj_b = (const float*)d_in[7];
  const float* ln2_g  = (const float*)d_in[8];
  const float* ln2_b  = (const float*)d_in[9];
  const float* mlp_w1 = (const float*)d_in[10];
  const float* mlp_b1 = (const float*)d_in[11];
  const float* mlp_w2 = (const float*)d_in[12];
  const float* mlp_b2 = (const float*)d_in[13];

  char* ws = (char*)d_ws;
  short* qkvbuf  = (short*)(ws);                 // [2048][6][3][49][32] bf16 = 115,605,504 B
  short* ln2b    = (short*)(ws);                 // [100352][192] bf16 spatial (aliases qkvbuf, dead by then)
  short* obuf    = (short*)(ws + 115605504);     // [100352][192] bf16
  short* hbuf    = (short*)(ws + 154140672);     // [100352][192] bf16 (ln1 out, window order)
  short* wT      = (short*)(ws + 192675840);
  short* qkv_wT  = wT;                            // 576*192
  short* proj_wT = wT + 110592;                   // 192*192
  short* m1_wT   = wT + 110592 + 36864;           // 768*192
  short* m2_wT   = wT + 110592 + 36864 + 147456;  // 192*768
  float* bm      = (float*)(ws + 193560576);      // [64][6][49][49] f32
  float* xout    = (float*)d_out;                 // x1 then final output

  transpose_w_k<<<(110592 + 255) / 256, 256, 0, stream>>>(qkv_w,  qkv_wT, 192, 576);
  transpose_w_k<<<(36864  + 255) / 256, 256, 0, stream>>>(proj_w, proj_wT, 192, 192);
  transpose_w_k<<<(147456 + 255) / 256, 256, 0, stream>>>(mlp_w1, m1_wT,  192, 768);
  transpose_w_k<<<(147456 + 255) / 256, 256, 0, stream>>>(mlp_w2, m2_wT,  768, 192);
  prep_bm_k<<<(64 * 6 * 2401 + 255) / 256, 256, 0, stream>>>(pos_b, bm);

  ln_k<<<25088, 256, 0, stream>>>(x, ln1_g, ln1_b, hbuf);
  gemm_qkv_k<<<dim3(9, 784), 256, 0, stream>>>(hbuf, qkv_wT, qkv_b, qkvbuf, 576, 192);
  attn_k<<<3072, 256, 0, stream>>>(qkvbuf, bm, obuf);
  proj_ln2_k<<<1568, 256, 0, stream>>>(obuf, proj_wT, proj_b, x, ln2_g, ln2_b, xout, ln2b);
  mlp_k<<<1568, 256, 0, stream>>>(ln2b, xout, m1_wT, mlp_b1, m2_wT, mlp_b2, xout);
}

// Round 4
// 530.004 us; speedup vs baseline: 1.1400x; 1.1400x over previous
//
#include <hip/hip_runtime.h>
#include <hip/hip_bf16.h>

typedef __attribute__((ext_vector_type(8))) short short8;
typedef __attribute__((ext_vector_type(4))) float floatx4;

#define SCALE_Q 0.17677669529663687f

__device__ __forceinline__ short f2bf(float f) {
  union { float f; unsigned u; } a; a.f = f;
  unsigned r = (a.u + 0x7FFFu + ((a.u >> 16) & 1u)) >> 16;
  return (short)r;
}

// window-order row -> spatial row index (reverse shift +3 roll), per reference
__device__ __forceinline__ int spatial_row(int r) {
  int n = r / 49, tw = r - n * 49;
  int bb = n >> 6, wdx = n & 63;
  int rh = (wdx >> 3) * 7 + tw / 7, rw = (wdx & 7) * 7 + tw % 7;
  int oh = rh + 3; if (oh >= 56) oh -= 56;
  int ow = rw + 3; if (ow >= 56) ow -= 56;
  return bb * 3136 + oh * 56 + ow;
}

// ---------- weight transpose + bf16: dst[n*K+k] = src[k*N+n] ----------
__global__ void transpose_w_k(const float* __restrict__ src, short* __restrict__ dst,
                              int K, int N) {
  int i = blockIdx.x * 256 + threadIdx.x;
  if (i >= N * K) return;
  int n = i / K, k = i - n * K;
  dst[i] = f2bf(src[(size_t)k * N + n]);
}

// ---------- fused pos_bias + shifted-window mask table: bm[w][h][49][49] ----------
__global__ void prep_bm_k(const float* __restrict__ pos_bias, float* __restrict__ bm) {
  int i = blockIdx.x * 256 + threadIdx.x;
  if (i >= 64 * 6 * 49 * 49) return;
  int j = i % 49; int t = i / 49; int ii = t % 49; t /= 49; int h = t % 6; int w = t / 6;
  int ih = ii / 7, iw = ii - ih * 7, jh = j / 7, jw = j - jh * 7;
  int rel = (ih - jh + 6) * 13 + (iw - jw + 6);
  float v = pos_bias[rel * 6 + h];
  int wh = w >> 3, ww = w & 7;
  int ri = wh * 7 + ih, ci = ww * 7 + iw, rj = wh * 7 + jh, cj = ww * 7 + jw;
  int regi = ((ri >= 49) + (ri >= 53)) * 3 + ((ci >= 49) + (ci >= 53));
  int regj = ((rj >= 49) + (rj >= 53)) * 3 + ((cj >= 49) + (cj >= 53));
  if (regi != regj) v -= 100.0f;
  bm[i] = v;
}

// ---------- LN1 + cyclic shift + window partition (one wave per row) ----------
__global__ __launch_bounds__(256) void ln_k(const float* __restrict__ x,
    const float* __restrict__ g, const float* __restrict__ bta,
    short* __restrict__ outb) {
  int wid = threadIdx.x >> 6, lane = threadIdx.x & 63;
  int r = blockIdx.x * 4 + wid;
  int n = r / 49, tw = r - n * 49;
  int bb = n >> 6, wdx = n & 63;
  int rh = (wdx >> 3) * 7 + tw / 7, rw = (wdx & 7) * 7 + tw % 7;
  int sh = rh + 3; if (sh >= 56) sh -= 56;
  int sw = rw + 3; if (sw >= 56) sw -= 56;
  size_t src = ((size_t)bb * 3136 + sh * 56 + sw) * 192;
  const float* xr = x + src;
  float v0 = xr[lane], v1 = xr[lane + 64], v2 = xr[lane + 128];
  float s = v0 + v1 + v2, sq = v0 * v0 + v1 * v1 + v2 * v2;
  #pragma unroll
  for (int o = 32; o >= 1; o >>= 1) { s += __shfl_xor(s, o); sq += __shfl_xor(sq, o); }
  float mean = s * (1.0f / 192.0f);
  float rstd = rsqrtf(sq * (1.0f / 192.0f) - mean * mean + 1e-5f);
  short* orow = outb + (size_t)r * 192;
  orow[lane]       = f2bf((v0 - mean) * rstd * g[lane]       + bta[lane]);
  orow[lane + 64]  = f2bf((v1 - mean) * rstd * g[lane + 64]  + bta[lane + 64]);
  orow[lane + 128] = f2bf((v2 - mean) * rstd * g[lane + 128] + bta[lane + 128]);
}

// ---------- QKV GEMM (128x64 tile, 4 waves) with head-scatter epilogue ----------
__global__ __launch_bounds__(256) void gemm_qkv_k(
    const short* __restrict__ A, const short* __restrict__ Bt,
    const float* __restrict__ bias, short* __restrict__ outp, int N, int K) {
  __shared__ short As[128][72];
  __shared__ short Bs[64][72];
  int tid = threadIdx.x;
  int gmb = blockIdx.y * 128;
  int gnb = blockIdx.x * 64;
  int wid = tid >> 6, lane = tid & 63;
  int wm = wid >> 1, wn = wid & 1;
  int lr = lane & 15, lk = (lane >> 4) << 3, lq = (lane >> 4) << 2;
  floatx4 acc[4][2];
  #pragma unroll
  for (int i = 0; i < 4; ++i)
    #pragma unroll
    for (int j = 0; j < 2; ++j) acc[i][j] = (floatx4)(0.0f);

  for (int k0 = 0; k0 < K; k0 += 64) {
    #pragma unroll
    for (int i = 0; i < 4; ++i) {
      int u = tid + 256 * i;
      int row = u >> 3, cb = (u & 7) << 3;
      *(short8*)&As[row][cb] = *(const short8*)&A[(size_t)(gmb + row) * K + k0 + cb];
    }
    #pragma unroll
    for (int i = 0; i < 2; ++i) {
      int u = tid + 256 * i;
      int row = u >> 3, cb = (u & 7) << 3;
      *(short8*)&Bs[row][cb] = *(const short8*)&Bt[(size_t)(gnb + row) * K + k0 + cb];
    }
    __syncthreads();
    #pragma unroll
    for (int kk = 0; kk < 64; kk += 32) {
      short8 af[4], bfr[2];
      #pragma unroll
      for (int mi = 0; mi < 4; ++mi)
        af[mi] = *(const short8*)&As[wm * 64 + mi * 16 + lr][kk + lk];
      #pragma unroll
      for (int ni = 0; ni < 2; ++ni)
        bfr[ni] = *(const short8*)&Bs[wn * 32 + ni * 16 + lr][kk + lk];
      #pragma unroll
      for (int mi = 0; mi < 4; ++mi)
        #pragma unroll
        for (int ni = 0; ni < 2; ++ni)
          acc[mi][ni] = __builtin_amdgcn_mfma_f32_16x16x32_bf16(af[mi], bfr[ni], acc[mi][ni], 0, 0, 0);
    }
    __syncthreads();
  }

  #pragma unroll
  for (int mi = 0; mi < 4; ++mi)
    #pragma unroll
    for (int ni = 0; ni < 2; ++ni)
      #pragma unroll
      for (int r = 0; r < 4; ++r) {
        int grow = gmb + wm * 64 + mi * 16 + lq + r;
        int gcol = gnb + wn * 32 + ni * 16 + lr;
        float v = acc[mi][ni][r] + bias[gcol];
        int which = gcol / 192, rem = gcol - which * 192;
        if (which == 0) v *= SCALE_Q;
        int head = rem >> 5, d = rem & 31;
        int n = grow / 49, tw = grow - n * 49;
        outp[((((size_t)(n * 6 + head) * 3 + which) * 49 + tw) << 5) + d] = f2bf(v);
      }
}

// ---------- window attention core: 1 wave per (window, head), NO softmax ----------
__global__ __launch_bounds__(256) void attn_k(const short* __restrict__ qkv,
    const float* __restrict__ bm, short* __restrict__ obuf) {
  __shared__ short lds[4][6912];
  int wid = threadIdx.x >> 6, lane = threadIdx.x & 63;
  int pair = blockIdx.x * 4 + wid;
  int n = pair / 6, h = pair - n * 6;
  short* Vt = &lds[wid][0];
  short* Ps = &lds[wid][32 * 72];
  const short* Qb = qkv + (size_t)((n * 6 + h) * 3) * 1568;
  const short* Kb = Qb + 1568;
  const short* Vb = Qb + 3136;
  int lr = lane & 15, lk = (lane >> 4) << 3, lq = (lane >> 4) << 2;

  #pragma unroll
  for (int it = 0; it < 8; ++it) {
    int u = lane + 64 * it;
    Vt[(u >> 4) * 72 + 48 + (u & 15)] = 0;
  }
  #pragma unroll
  for (int it = 0; it < 4; ++it) {
    int u = lane + 64 * it;
    if (u < 196) {
      int tw = u >> 2, db = (u & 3) << 3;
      short8 vv = *(const short8*)&Vb[tw * 32 + db];
      #pragma unroll
      for (int j = 0; j < 8; ++j) Vt[(db + j) * 72 + tw] = vv[j];
    }
  }

  short8 qf[4], kf[4];
  #pragma unroll
  for (int mi = 0; mi < 4; ++mi)
    qf[mi] = *(const short8*)&Qb[(mi * 16 + lr) * 32 + lk];
  #pragma unroll
  for (int nj = 0; nj < 4; ++nj)
    kf[nj] = *(const short8*)&Kb[(nj * 16 + lr) * 32 + lk];
  floatx4 s[4][4];
  #pragma unroll
  for (int mi = 0; mi < 4; ++mi)
    #pragma unroll
    for (int nj = 0; nj < 4; ++nj)
      s[mi][nj] = __builtin_amdgcn_mfma_f32_16x16x32_bf16(qf[mi], kf[nj], (floatx4)(0.0f), 0, 0, 0);

  const float* bmw = bm + (size_t)((n & 63) * 6 + h) * 2401;
  #pragma unroll
  for (int mi = 0; mi < 4; ++mi)
    #pragma unroll
    for (int nj = 0; nj < 4; ++nj)
      #pragma unroll
      for (int r = 0; r < 4; ++r) {
        int i = mi * 16 + lq + r;
        int j = nj * 16 + lr;
        float v = 0.0f;
        if (i < 49 && j < 49) v = s[mi][nj][r] + bmw[i * 49 + j];
        Ps[i * 72 + j] = f2bf(v);
      }

  floatx4 o[4][2];
  #pragma unroll
  for (int mi = 0; mi < 4; ++mi)
    #pragma unroll
    for (int ni = 0; ni < 2; ++ni) o[mi][ni] = (floatx4)(0.0f);
  #pragma unroll
  for (int kc = 0; kc < 2; ++kc) {
    short8 pf[4], vf[2];
    #pragma unroll
    for (int mi = 0; mi < 4; ++mi)
      pf[mi] = *(const short8*)&Ps[(mi * 16 + lr) * 72 + kc * 32 + lk];
    #pragma unroll
    for (int ni = 0; ni < 2; ++ni)
      vf[ni] = *(const short8*)&Vt[(ni * 16 + lr) * 72 + kc * 32 + lk];
    #pragma unroll
    for (int mi = 0; mi < 4; ++mi)
      #pragma unroll
      for (int ni = 0; ni < 2; ++ni)
        o[mi][ni] = __builtin_amdgcn_mfma_f32_16x16x32_bf16(pf[mi], vf[ni], o[mi][ni], 0, 0, 0);
  }
  #pragma unroll
  for (int mi = 0; mi < 4; ++mi)
    #pragma unroll
    for (int ni = 0; ni < 2; ++ni)
      #pragma unroll
      for (int r = 0; r < 4; ++r) {
        int i = mi * 16 + lq + r;
        if (i < 49)
          obuf[((size_t)n * 49 + i) * 192 + h * 32 + ni * 16 + lr] = f2bf(o[mi][ni][r]);
      }
}

// ---------- proj GEMM (staged, 128 x full-192 tile) + residual + LN2 epilogue ----------
// 512 threads, 8 waves (wm 0..1 x wn 0..3). K=192 staged in 3 steps.
__global__ __launch_bounds__(512) void proj_ln2_k(
    const short* __restrict__ obuf, const short* __restrict__ projT,
    const float* __restrict__ proj_b, const float* __restrict__ x,
    const float* __restrict__ g2, const float* __restrict__ bt2,
    float* __restrict__ x1out, short* __restrict__ ln2out) {
  __shared__ short As[128][72];
  __shared__ short Bs[192][72];
  __shared__ float sums[128][4][2];
  __shared__ float stats[128][2];
  int tid = threadIdx.x;
  int wid = tid >> 6, lane = tid & 63;
  int wm = wid >> 2, wn = wid & 3;
  int lr = lane & 15, lk = (lane >> 4) << 3, lq = (lane >> 4) << 2;
  int R0 = blockIdx.x * 128;

  floatx4 acc[4][3];
  #pragma unroll
  for (int mi = 0; mi < 4; ++mi)
    #pragma unroll
    for (int ni = 0; ni < 3; ++ni) acc[mi][ni] = (floatx4)(0.0f);

  for (int k0 = 0; k0 < 192; k0 += 64) {
    #pragma unroll
    for (int i = 0; i < 2; ++i) {
      int u = tid + 512 * i;
      int row = u >> 3, cb = (u & 7) << 3;
      *(short8*)&As[row][cb] = *(const short8*)&obuf[(size_t)(R0 + row) * 192 + k0 + cb];
    }
    #pragma unroll
    for (int i = 0; i < 3; ++i) {
      int u = tid + 512 * i;
      int row = u >> 3, cb = (u & 7) << 3;
      *(short8*)&Bs[row][cb] = *(const short8*)&projT[(size_t)row * 192 + k0 + cb];
    }
    __syncthreads();
    #pragma unroll
    for (int kk = 0; kk < 64; kk += 32) {
      short8 af[4], bfr[3];
      #pragma unroll
      for (int mi = 0; mi < 4; ++mi)
        af[mi] = *(const short8*)&As[wm * 64 + mi * 16 + lr][kk + lk];
      #pragma unroll
      for (int ni = 0; ni < 3; ++ni)
        bfr[ni] = *(const short8*)&Bs[wn * 48 + ni * 16 + lr][kk + lk];
      #pragma unroll
      for (int mi = 0; mi < 4; ++mi)
        #pragma unroll
        for (int ni = 0; ni < 3; ++ni)
          acc[mi][ni] = __builtin_amdgcn_mfma_f32_16x16x32_bf16(af[mi], bfr[ni], acc[mi][ni], 0, 0, 0);
    }
    __syncthreads();
  }

  int col[3]; float pb[3], gv[3], bv[3];
  #pragma unroll
  for (int ni = 0; ni < 3; ++ni) {
    col[ni] = wn * 48 + ni * 16 + lr;
    pb[ni] = proj_b[col[ni]];
    gv[ni] = g2[col[ni]];
    bv[ni] = bt2[col[ni]];
  }

  int srw[4][4];
  #pragma unroll
  for (int mi = 0; mi < 4; ++mi)
    #pragma unroll
    for (int rr = 0; rr < 4; ++rr) {
      int row_l = wm * 64 + mi * 16 + lq + rr;
      int sr = spatial_row(R0 + row_l);
      srw[mi][rr] = sr;
      float s = 0.0f, sq = 0.0f;
      #pragma unroll
      for (int ni = 0; ni < 3; ++ni) {
        float v = acc[mi][ni][rr] + pb[ni] + x[(size_t)sr * 192 + col[ni]];
        acc[mi][ni][rr] = v;
        s += v; sq += v * v;
      }
      #pragma unroll
      for (int o = 8; o >= 1; o >>= 1) { s += __shfl_xor(s, o); sq += __shfl_xor(sq, o); }
      if (lr == 0) { sums[row_l][wn][0] = s; sums[row_l][wn][1] = sq; }
    }
  __syncthreads();
  if (tid < 128) {
    float s = sums[tid][0][0] + sums[tid][1][0] + sums[tid][2][0] + sums[tid][3][0];
    float sq = sums[tid][0][1] + sums[tid][1][1] + sums[tid][2][1] + sums[tid][3][1];
    float mean = s * (1.0f / 192.0f);
    float var = sq * (1.0f / 192.0f) - mean * mean;
    stats[tid][0] = mean;
    stats[tid][1] = rsqrtf(var + 1e-5f);
  }
  __syncthreads();

  #pragma unroll
  for (int mi = 0; mi < 4; ++mi)
    #pragma unroll
    for (int rr = 0; rr < 4; ++rr) {
      int row_l = wm * 64 + mi * 16 + lq + rr;
      int sr = srw[mi][rr];
      float mean = stats[row_l][0], rstd = stats[row_l][1];
      #pragma unroll
      for (int ni = 0; ni < 3; ++ni) {
        float v = acc[mi][ni][rr];
        x1out[(size_t)sr * 192 + col[ni]] = v;
        ln2out[(size_t)sr * 192 + col[ni]] = f2bf((v - mean) * rstd * gv[ni] + bv[ni]);
      }
    }
}

// ---------- MLP1 GEMM (staged, 128x128 tile, 512 thr) + gelu -> hidden bf16 ----------
__global__ __launch_bounds__(512) void mlp1_k(
    const short* __restrict__ A, const short* __restrict__ w1T,
    const float* __restrict__ b1, short* __restrict__ hidden) {
  __shared__ short As[128][72];
  __shared__ short Bs[128][72];
  int tid = threadIdx.x;
  int wid = tid >> 6, lane = tid & 63;
  int wm = wid >> 2, wn = wid & 3;
  int lr = lane & 15, lk = (lane >> 4) << 3, lq = (lane >> 4) << 2;
  int R0 = blockIdx.y * 128;
  int N0 = blockIdx.x * 128;

  floatx4 acc[4][2];
  #pragma unroll
  for (int mi = 0; mi < 4; ++mi)
    #pragma unroll
    for (int ni = 0; ni < 2; ++ni) acc[mi][ni] = (floatx4)(0.0f);

  for (int k0 = 0; k0 < 192; k0 += 64) {
    #pragma unroll
    for (int i = 0; i < 2; ++i) {
      int u = tid + 512 * i;
      int row = u >> 3, cb = (u & 7) << 3;
      *(short8*)&As[row][cb] = *(const short8*)&A[(size_t)(R0 + row) * 192 + k0 + cb];
      *(short8*)&Bs[row][cb] = *(const short8*)&w1T[(size_t)(N0 + row) * 192 + k0 + cb];
    }
    __syncthreads();
    #pragma unroll
    for (int kk = 0; kk < 64; kk += 32) {
      short8 af[4], bfr[2];
      #pragma unroll
      for (int mi = 0; mi < 4; ++mi)
        af[mi] = *(const short8*)&As[wm * 64 + mi * 16 + lr][kk + lk];
      #pragma unroll
      for (int ni = 0; ni < 2; ++ni)
        bfr[ni] = *(const short8*)&Bs[wn * 32 + ni * 16 + lr][kk + lk];
      #pragma unroll
      for (int mi = 0; mi < 4; ++mi)
        #pragma unroll
        for (int ni = 0; ni < 2; ++ni)
          acc[mi][ni] = __builtin_amdgcn_mfma_f32_16x16x32_bf16(af[mi], bfr[ni], acc[mi][ni], 0, 0, 0);
    }
    __syncthreads();
  }

  #pragma unroll
  for (int ni = 0; ni < 2; ++ni) {
    int gcol = N0 + wn * 32 + ni * 16 + lr;
    float b1v = b1[gcol];
    #pragma unroll
    for (int mi = 0; mi < 4; ++mi)
      #pragma unroll
      for (int rr = 0; rr < 4; ++rr) {
        int grow = R0 + wm * 64 + mi * 16 + lq + rr;
        float hv = acc[mi][ni][rr] + b1v;
        float ge = 0.5f * hv * (1.0f + erff(hv * 0.70710678118f));
        hidden[(size_t)grow * 768 + gcol] = f2bf(ge);
      }
  }
}

// ---------- MLP2 GEMM (staged, 128 x full-192 tile, K=768) + final residual ----------
__global__ __launch_bounds__(512) void mlp2_k(
    const short* __restrict__ hidden, const float* __restrict__ x1,
    const short* __restrict__ w2T, const float* __restrict__ b2,
    float* __restrict__ out) {
  __shared__ short As[128][72];
  __shared__ short Bs[192][72];
  int tid = threadIdx.x;
  int wid = tid >> 6, lane = tid & 63;
  int wm = wid >> 2, wn = wid & 3;
  int lr = lane & 15, lk = (lane >> 4) << 3, lq = (lane >> 4) << 2;
  int R0 = blockIdx.x * 128;

  floatx4 acc[4][3];
  #pragma unroll
  for (int mi = 0; mi < 4; ++mi)
    #pragma unroll
    for (int ni = 0; ni < 3; ++ni) acc[mi][ni] = (floatx4)(0.0f);

  for (int k0 = 0; k0 < 768; k0 += 64) {
    #pragma unroll
    for (int i = 0; i < 2; ++i) {
      int u = tid + 512 * i;
      int row = u >> 3, cb = (u & 7) << 3;
      *(short8*)&As[row][cb] = *(const short8*)&hidden[(size_t)(R0 + row) * 768 + k0 + cb];
    }
    #pragma unroll
    for (int i = 0; i < 3; ++i) {
      int u = tid + 512 * i;
      int row = u >> 3, cb = (u & 7) << 3;
      *(short8*)&Bs[row][cb] = *(const short8*)&w2T[(size_t)row * 768 + k0 + cb];
    }
    __syncthreads();
    #pragma unroll
    for (int kk = 0; kk < 64; kk += 32) {
      short8 af[4], bfr[3];
      #pragma unroll
      for (int mi = 0; mi < 4; ++mi)
        af[mi] = *(const short8*)&As[wm * 64 + mi * 16 + lr][kk + lk];
      #pragma unroll
      for (int ni = 0; ni < 3; ++ni)
        bfr[ni] = *(const short8*)&Bs[wn * 48 + ni * 16 + lr][kk + lk];
      #pragma unroll
      for (int mi = 0; mi < 4; ++mi)
        #pragma unroll
        for (int ni = 0; ni < 3; ++ni)
          acc[mi][ni] = __builtin_amdgcn_mfma_f32_16x16x32_bf16(af[mi], bfr[ni], acc[mi][ni], 0, 0, 0);
    }
    __syncthreads();
  }

  #pragma unroll
  for (int ni = 0; ni < 3; ++ni) {
    int gcol = wn * 48 + ni * 16 + lr;
    float b2v = b2[gcol];
    #pragma unroll
    for (int mi = 0; mi < 4; ++mi)
      #pragma unroll
      for (int rr = 0; rr < 4; ++rr) {
        size_t r = (size_t)(R0 + wm * 64 + mi * 16 + lq + rr) * 192;
        out[r + gcol] = x1[r + gcol] + acc[mi][ni][rr] + b2v;
      }
  }
}

extern "C" void kernel_launch(void* const* d_in, const int* in_sizes, int n_in,
                              void* d_out, int out_size, void* d_ws, size_t ws_size,
                              hipStream_t stream) {
  const float* x      = (const float*)d_in[0];
  const float* ln1_g  = (const float*)d_in[1];
  const float* ln1_b  = (const float*)d_in[2];
  const float* qkv_w  = (const float*)d_in[3];
  const float* qkv_b  = (const float*)d_in[4];
  const float* pos_b  = (const float*)d_in[5];
  const float* proj_w = (const float*)d_in[6];
  const float* proj_b = (const float*)d_in[7];
  const float* ln2_g  = (const float*)d_in[8];
  const float* ln2_b  = (const float*)d_in[9];
  const float* mlp_w1 = (const float*)d_in[10];
  const float* mlp_b1 = (const float*)d_in[11];
  const float* mlp_w2 = (const float*)d_in[12];
  const float* mlp_b2 = (const float*)d_in[13];

  char* ws = (char*)d_ws;
  short* qkvbuf  = (short*)(ws);                 // 115.6 MB (dead after attn)
  short* hidden  = (short*)(ws);                 // [100352][768] bf16, aliases qkvbuf+obuf
  short* obuf    = (short*)(ws + 115605504);     // 38.5 MB (dead after proj_ln2)
  short* hbuf    = (short*)(ws + 154140672);     // ln1 out (dead after qkv)
  short* ln2b    = (short*)(ws + 154140672);     // ln2 out (aliases hbuf, spatial order)
  short* wT      = (short*)(ws + 192675840);
  short* qkv_wT  = wT;                            // 576*192
  short* proj_wT = wT + 110592;                   // 192*192
  short* m1_wT   = wT + 110592 + 36864;           // 768*192
  short* m2_wT   = wT + 110592 + 36864 + 147456;  // 192*768
  float* bm      = (float*)(ws + 193560576);      // [64][6][49][49] f32
  float* xout    = (float*)d_out;                 // x1 then final output

  transpose_w_k<<<(110592 + 255) / 256, 256, 0, stream>>>(qkv_w,  qkv_wT, 192, 576);
  transpose_w_k<<<(36864  + 255) / 256, 256, 0, stream>>>(proj_w, proj_wT, 192, 192);
  transpose_w_k<<<(147456 + 255) / 256, 256, 0, stream>>>(mlp_w1, m1_wT,  192, 768);
  transpose_w_k<<<(147456 + 255) / 256, 256, 0, stream>>>(mlp_w2, m2_wT,  768, 192);
  prep_bm_k<<<(64 * 6 * 2401 + 255) / 256, 256, 0, stream>>>(pos_b, bm);

  ln_k<<<25088, 256, 0, stream>>>(x, ln1_g, ln1_b, hbuf);
  gemm_qkv_k<<<dim3(9, 784), 256, 0, stream>>>(hbuf, qkv_wT, qkv_b, qkvbuf, 576, 192);
  attn_k<<<3072, 256, 0, stream>>>(qkvbuf, bm, obuf);
  proj_ln2_k<<<784, 512, 0, stream>>>(obuf, proj_wT, proj_b, x, ln2_g, ln2_b, xout, ln2b);
  mlp1_k<<<dim3(6, 784), 512, 0, stream>>>(ln2b, m1_wT, mlp_b1, hidden);
  mlp2_k<<<784, 512, 0, stream>>>(hidden, xout, m2_wT, mlp_b2, xout);
}

// Round 5
// 498.633 us; speedup vs baseline: 1.2118x; 1.0629x over previous
//
#include <hip/hip_runtime.h>
#include <hip/hip_bf16.h>

typedef __attribute__((ext_vector_type(8))) short short8;
typedef __attribute__((ext_vector_type(4))) float floatx4;

#define SCALE_Q 0.17677669529663687f

__device__ __forceinline__ short f2bf(float f) {
  union { float f; unsigned u; } a; a.f = f;
  unsigned r = (a.u + 0x7FFFu + ((a.u >> 16) & 1u)) >> 16;
  return (short)r;
}

// window-order row -> spatial row index (reverse shift +3 roll), per reference
__device__ __forceinline__ int spatial_row(int r) {
  int n = r / 49, tw = r - n * 49;
  int bb = n >> 6, wdx = n & 63;
  int rh = (wdx >> 3) * 7 + tw / 7, rw = (wdx & 7) * 7 + tw % 7;
  int oh = rh + 3; if (oh >= 56) oh -= 56;
  int ow = rw + 3; if (ow >= 56) ow -= 56;
  return bb * 3136 + oh * 56 + ow;
}

// ---------- weight transpose + bf16: dst[n*K+k] = src[k*N+n] ----------
__global__ void transpose_w_k(const float* __restrict__ src, short* __restrict__ dst,
                              int K, int N) {
  int i = blockIdx.x * 256 + threadIdx.x;
  if (i >= N * K) return;
  int n = i / K, k = i - n * K;
  dst[i] = f2bf(src[(size_t)k * N + n]);
}

// ---------- fused pos_bias + shifted-window mask table: bm[w][h][49][49] ----------
__global__ void prep_bm_k(const float* __restrict__ pos_bias, float* __restrict__ bm) {
  int i = blockIdx.x * 256 + threadIdx.x;
  if (i >= 64 * 6 * 49 * 49) return;
  int j = i % 49; int t = i / 49; int ii = t % 49; t /= 49; int h = t % 6; int w = t / 6;
  int ih = ii / 7, iw = ii - ih * 7, jh = j / 7, jw = j - jh * 7;
  int rel = (ih - jh + 6) * 13 + (iw - jw + 6);
  float v = pos_bias[rel * 6 + h];
  int wh = w >> 3, ww = w & 7;
  int ri = wh * 7 + ih, ci = ww * 7 + iw, rj = wh * 7 + jh, cj = ww * 7 + jw;
  int regi = ((ri >= 49) + (ri >= 53)) * 3 + ((ci >= 49) + (ci >= 53));
  int regj = ((rj >= 49) + (rj >= 53)) * 3 + ((cj >= 49) + (cj >= 53));
  if (regi != regj) v -= 100.0f;
  bm[i] = v;
}

// ---------- LN1 + cyclic shift + window partition (one wave per row) ----------
__global__ __launch_bounds__(256) void ln_k(const float* __restrict__ x,
    const float* __restrict__ g, const float* __restrict__ bta,
    short* __restrict__ outb) {
  int wid = threadIdx.x >> 6, lane = threadIdx.x & 63;
  int r = blockIdx.x * 4 + wid;
  int n = r / 49, tw = r - n * 49;
  int bb = n >> 6, wdx = n & 63;
  int rh = (wdx >> 3) * 7 + tw / 7, rw = (wdx & 7) * 7 + tw % 7;
  int sh = rh + 3; if (sh >= 56) sh -= 56;
  int sw = rw + 3; if (sw >= 56) sw -= 56;
  size_t src = ((size_t)bb * 3136 + sh * 56 + sw) * 192;
  const float* xr = x + src;
  float v0 = xr[lane], v1 = xr[lane + 64], v2 = xr[lane + 128];
  float s = v0 + v1 + v2, sq = v0 * v0 + v1 * v1 + v2 * v2;
  #pragma unroll
  for (int o = 32; o >= 1; o >>= 1) { s += __shfl_xor(s, o); sq += __shfl_xor(sq, o); }
  float mean = s * (1.0f / 192.0f);
  float rstd = rsqrtf(sq * (1.0f / 192.0f) - mean * mean + 1e-5f);
  short* orow = outb + (size_t)r * 192;
  orow[lane]       = f2bf((v0 - mean) * rstd * g[lane]       + bta[lane]);
  orow[lane + 64]  = f2bf((v1 - mean) * rstd * g[lane + 64]  + bta[lane + 64]);
  orow[lane + 128] = f2bf((v2 - mean) * rstd * g[lane + 128] + bta[lane + 128]);
}

// ---------- pipelined bf16 MFMA GEMM, 128x64 tile, 4 waves, reg-prefetch ----------
// loop: {ds_write(regs); bar; issue loads k+1 -> regs; compute k; bar}
// EPI 0: QKV scatter   2: +gelu -> hidden   3: out = x1 + m + b
template<int EPI>
__global__ __launch_bounds__(256) void pgemm_k(
    const short* __restrict__ A, const short* __restrict__ Bt,
    const float* __restrict__ bias, void* __restrict__ outp,
    const void* __restrict__ aux, int N, int K) {
  __shared__ short As[128][72];
  __shared__ short Bs[64][72];
  int tid = threadIdx.x;
  int gmb = blockIdx.y * 128;
  int gnb = blockIdx.x * 64;
  int wid = tid >> 6, lane = tid & 63;
  int wm = wid >> 1, wn = wid & 1;
  int lr = lane & 15, lk = (lane >> 4) << 3, lq = (lane >> 4) << 2;
  int ar = tid >> 3, ac = (tid & 7) << 3;   // staging row (0..31), col chunk

  floatx4 acc[4][2];
  #pragma unroll
  for (int i = 0; i < 4; ++i)
    #pragma unroll
    for (int j = 0; j < 2; ++j) acc[i][j] = (floatx4)(0.0f);

  // prologue: load K-tile 0 into regs
  short8 pa[4], pb[2];
  #pragma unroll
  for (int i = 0; i < 4; ++i)
    pa[i] = *(const short8*)&A[(size_t)(gmb + ar + 32 * i) * K + ac];
  #pragma unroll
  for (int i = 0; i < 2; ++i)
    pb[i] = *(const short8*)&Bt[(size_t)(gnb + ar + 32 * i) * K + ac];

  for (int k0 = 0; k0 < K; k0 += 64) {
    #pragma unroll
    for (int i = 0; i < 4; ++i) *(short8*)&As[ar + 32 * i][ac] = pa[i];
    #pragma unroll
    for (int i = 0; i < 2; ++i) *(short8*)&Bs[ar + 32 * i][ac] = pb[i];
    __syncthreads();
    if (k0 + 64 < K) {   // issue next-tile loads; in flight during compute
      #pragma unroll
      for (int i = 0; i < 4; ++i)
        pa[i] = *(const short8*)&A[(size_t)(gmb + ar + 32 * i) * K + k0 + 64 + ac];
      #pragma unroll
      for (int i = 0; i < 2; ++i)
        pb[i] = *(const short8*)&Bt[(size_t)(gnb + ar + 32 * i) * K + k0 + 64 + ac];
    }
    #pragma unroll
    for (int kk = 0; kk < 64; kk += 32) {
      short8 af[4], bfr[2];
      #pragma unroll
      for (int mi = 0; mi < 4; ++mi)
        af[mi] = *(const short8*)&As[wm * 64 + mi * 16 + lr][kk + lk];
      #pragma unroll
      for (int ni = 0; ni < 2; ++ni)
        bfr[ni] = *(const short8*)&Bs[wn * 32 + ni * 16 + lr][kk + lk];
      #pragma unroll
      for (int mi = 0; mi < 4; ++mi)
        #pragma unroll
        for (int ni = 0; ni < 2; ++ni)
          acc[mi][ni] = __builtin_amdgcn_mfma_f32_16x16x32_bf16(af[mi], bfr[ni], acc[mi][ni], 0, 0, 0);
    }
    __syncthreads();
  }

  #pragma unroll
  for (int mi = 0; mi < 4; ++mi)
    #pragma unroll
    for (int ni = 0; ni < 2; ++ni)
      #pragma unroll
      for (int r = 0; r < 4; ++r) {
        int grow = gmb + wm * 64 + mi * 16 + lq + r;
        int gcol = gnb + wn * 32 + ni * 16 + lr;
        float v = acc[mi][ni][r] + bias[gcol];
        if (EPI == 0) {
          int which = gcol / 192, rem = gcol - which * 192;
          if (which == 0) v *= SCALE_Q;
          int head = rem >> 5, d = rem & 31;
          int n = grow / 49, tw = grow - n * 49;
          ((short*)outp)[((((size_t)(n * 6 + head) * 3 + which) * 49 + tw) << 5) + d] = f2bf(v);
        } else if (EPI == 2) {
          float ge = 0.5f * v * (1.0f + erff(v * 0.70710678118f));
          ((short*)outp)[(size_t)grow * 768 + gcol] = f2bf(ge);
        } else {
          size_t idx = (size_t)grow * 192 + gcol;
          ((float*)outp)[idx] = ((const float*)aux)[idx] + v;
        }
      }
}

// ---------- window attention core: 1 wave per (window, head), NO softmax ----------
__global__ __launch_bounds__(256) void attn_k(const short* __restrict__ qkv,
    const float* __restrict__ bm, short* __restrict__ obuf) {
  __shared__ short lds[4][6912];
  int wid = threadIdx.x >> 6, lane = threadIdx.x & 63;
  int pair = blockIdx.x * 4 + wid;
  int n = pair / 6, h = pair - n * 6;
  short* Vt = &lds[wid][0];
  short* Ps = &lds[wid][32 * 72];
  const short* Qb = qkv + (size_t)((n * 6 + h) * 3) * 1568;
  const short* Kb = Qb + 1568;
  const short* Vb = Qb + 3136;
  int lr = lane & 15, lk = (lane >> 4) << 3, lq = (lane >> 4) << 2;

  #pragma unroll
  for (int it = 0; it < 8; ++it) {
    int u = lane + 64 * it;
    Vt[(u >> 4) * 72 + 48 + (u & 15)] = 0;
  }
  #pragma unroll
  for (int it = 0; it < 4; ++it) {
    int u = lane + 64 * it;
    if (u < 196) {
      int tw = u >> 2, db = (u & 3) << 3;
      short8 vv = *(const short8*)&Vb[tw * 32 + db];
      #pragma unroll
      for (int j = 0; j < 8; ++j) Vt[(db + j) * 72 + tw] = vv[j];
    }
  }

  short8 qf[4], kf[4];
  #pragma unroll
  for (int mi = 0; mi < 4; ++mi)
    qf[mi] = *(const short8*)&Qb[(mi * 16 + lr) * 32 + lk];
  #pragma unroll
  for (int nj = 0; nj < 4; ++nj)
    kf[nj] = *(const short8*)&Kb[(nj * 16 + lr) * 32 + lk];
  floatx4 s[4][4];
  #pragma unroll
  for (int mi = 0; mi < 4; ++mi)
    #pragma unroll
    for (int nj = 0; nj < 4; ++nj)
      s[mi][nj] = __builtin_amdgcn_mfma_f32_16x16x32_bf16(qf[mi], kf[nj], (floatx4)(0.0f), 0, 0, 0);

  const float* bmw = bm + (size_t)((n & 63) * 6 + h) * 2401;
  #pragma unroll
  for (int mi = 0; mi < 4; ++mi)
    #pragma unroll
    for (int nj = 0; nj < 4; ++nj)
      #pragma unroll
      for (int r = 0; r < 4; ++r) {
        int i = mi * 16 + lq + r;
        int j = nj * 16 + lr;
        float v = 0.0f;
        if (i < 49 && j < 49) v = s[mi][nj][r] + bmw[i * 49 + j];
        Ps[i * 72 + j] = f2bf(v);
      }

  floatx4 o[4][2];
  #pragma unroll
  for (int mi = 0; mi < 4; ++mi)
    #pragma unroll
    for (int ni = 0; ni < 2; ++ni) o[mi][ni] = (floatx4)(0.0f);
  #pragma unroll
  for (int kc = 0; kc < 2; ++kc) {
    short8 pf[4], vf[2];
    #pragma unroll
    for (int mi = 0; mi < 4; ++mi)
      pf[mi] = *(const short8*)&Ps[(mi * 16 + lr) * 72 + kc * 32 + lk];
    #pragma unroll
    for (int ni = 0; ni < 2; ++ni)
      vf[ni] = *(const short8*)&Vt[(ni * 16 + lr) * 72 + kc * 32 + lk];
    #pragma unroll
    for (int mi = 0; mi < 4; ++mi)
      #pragma unroll
      for (int ni = 0; ni < 2; ++ni)
        o[mi][ni] = __builtin_amdgcn_mfma_f32_16x16x32_bf16(pf[mi], vf[ni], o[mi][ni], 0, 0, 0);
  }
  #pragma unroll
  for (int mi = 0; mi < 4; ++mi)
    #pragma unroll
    for (int ni = 0; ni < 2; ++ni)
      #pragma unroll
      for (int r = 0; r < 4; ++r) {
        int i = mi * 16 + lq + r;
        if (i < 49)
          obuf[((size_t)n * 49 + i) * 192 + h * 32 + ni * 16 + lr] = f2bf(o[mi][ni][r]);
      }
}

// ---------- proj GEMM (reg-prefetch, 128 x full-192 tile) + residual + LN2 ----------
__global__ __launch_bounds__(512) void proj_ln2_k(
    const short* __restrict__ obuf, const short* __restrict__ projT,
    const float* __restrict__ proj_b, const float* __restrict__ x,
    const float* __restrict__ g2, const float* __restrict__ bt2,
    float* __restrict__ x1out, short* __restrict__ ln2out) {
  __shared__ short As[128][72];
  __shared__ short Bs[192][72];
  __shared__ float sums[128][4][2];
  __shared__ float stats[128][2];
  int tid = threadIdx.x;
  int wid = tid >> 6, lane = tid & 63;
  int wm = wid >> 2, wn = wid & 3;
  int lr = lane & 15, lk = (lane >> 4) << 3, lq = (lane >> 4) << 2;
  int R0 = blockIdx.x * 128;
  int ar = tid >> 3, ac = (tid & 7) << 3;   // ar 0..63

  floatx4 acc[4][3];
  #pragma unroll
  for (int mi = 0; mi < 4; ++mi)
    #pragma unroll
    for (int ni = 0; ni < 3; ++ni) acc[mi][ni] = (floatx4)(0.0f);

  short8 pa[2], pbr[3];
  #pragma unroll
  for (int i = 0; i < 2; ++i)
    pa[i] = *(const short8*)&obuf[(size_t)(R0 + ar + 64 * i) * 192 + ac];
  #pragma unroll
  for (int i = 0; i < 3; ++i)
    pbr[i] = *(const short8*)&projT[(size_t)(ar + 64 * i) * 192 + ac];

  for (int k0 = 0; k0 < 192; k0 += 64) {
    #pragma unroll
    for (int i = 0; i < 2; ++i) *(short8*)&As[ar + 64 * i][ac] = pa[i];
    #pragma unroll
    for (int i = 0; i < 3; ++i) *(short8*)&Bs[ar + 64 * i][ac] = pbr[i];
    __syncthreads();
    if (k0 < 128) {
      #pragma unroll
      for (int i = 0; i < 2; ++i)
        pa[i] = *(const short8*)&obuf[(size_t)(R0 + ar + 64 * i) * 192 + k0 + 64 + ac];
      #pragma unroll
      for (int i = 0; i < 3; ++i)
        pbr[i] = *(const short8*)&projT[(size_t)(ar + 64 * i) * 192 + k0 + 64 + ac];
    }
    #pragma unroll
    for (int kk = 0; kk < 64; kk += 32) {
      short8 af[4], bfr[3];
      #pragma unroll
      for (int mi = 0; mi < 4; ++mi)
        af[mi] = *(const short8*)&As[wm * 64 + mi * 16 + lr][kk + lk];
      #pragma unroll
      for (int ni = 0; ni < 3; ++ni)
        bfr[ni] = *(const short8*)&Bs[wn * 48 + ni * 16 + lr][kk + lk];
      #pragma unroll
      for (int mi = 0; mi < 4; ++mi)
        #pragma unroll
        for (int ni = 0; ni < 3; ++ni)
          acc[mi][ni] = __builtin_amdgcn_mfma_f32_16x16x32_bf16(af[mi], bfr[ni], acc[mi][ni], 0, 0, 0);
    }
    __syncthreads();
  }

  int col[3]; float pb[3], gv[3], bv[3];
  #pragma unroll
  for (int ni = 0; ni < 3; ++ni) {
    col[ni] = wn * 48 + ni * 16 + lr;
    pb[ni] = proj_b[col[ni]];
    gv[ni] = g2[col[ni]];
    bv[ni] = bt2[col[ni]];
  }

  int srw[4][4];
  #pragma unroll
  for (int mi = 0; mi < 4; ++mi)
    #pragma unroll
    for (int rr = 0; rr < 4; ++rr) {
      int row_l = wm * 64 + mi * 16 + lq + rr;
      int sr = spatial_row(R0 + row_l);
      srw[mi][rr] = sr;
      float s = 0.0f, sq = 0.0f;
      #pragma unroll
      for (int ni = 0; ni < 3; ++ni) {
        float v = acc[mi][ni][rr] + pb[ni] + x[(size_t)sr * 192 + col[ni]];
        acc[mi][ni][rr] = v;
        s += v; sq += v * v;
      }
      #pragma unroll
      for (int o = 8; o >= 1; o >>= 1) { s += __shfl_xor(s, o); sq += __shfl_xor(sq, o); }
      if (lr == 0) { sums[row_l][wn][0] = s; sums[row_l][wn][1] = sq; }
    }
  __syncthreads();
  if (tid < 128) {
    float s = sums[tid][0][0] + sums[tid][1][0] + sums[tid][2][0] + sums[tid][3][0];
    float sq = sums[tid][0][1] + sums[tid][1][1] + sums[tid][2][1] + sums[tid][3][1];
    float mean = s * (1.0f / 192.0f);
    float var = sq * (1.0f / 192.0f) - mean * mean;
    stats[tid][0] = mean;
    stats[tid][1] = rsqrtf(var + 1e-5f);
  }
  __syncthreads();

  #pragma unroll
  for (int mi = 0; mi < 4; ++mi)
    #pragma unroll
    for (int rr = 0; rr < 4; ++rr) {
      int row_l = wm * 64 + mi * 16 + lq + rr;
      int sr = srw[mi][rr];
      float mean = stats[row_l][0], rstd = stats[row_l][1];
      #pragma unroll
      for (int ni = 0; ni < 3; ++ni) {
        float v = acc[mi][ni][rr];
        x1out[(size_t)sr * 192 + col[ni]] = v;
        ln2out[(size_t)sr * 192 + col[ni]] = f2bf((v - mean) * rstd * gv[ni] + bv[ni]);
      }
    }
}

extern "C" void kernel_launch(void* const* d_in, const int* in_sizes, int n_in,
                              void* d_out, int out_size, void* d_ws, size_t ws_size,
                              hipStream_t stream) {
  const float* x      = (const float*)d_in[0];
  const float* ln1_g  = (const float*)d_in[1];
  const float* ln1_b  = (const float*)d_in[2];
  const float* qkv_w  = (const float*)d_in[3];
  const float* qkv_b  = (const float*)d_in[4];
  const float* pos_b  = (const float*)d_in[5];
  const float* proj_w = (const float*)d_in[6];
  const float* proj_b = (const float*)d_in[7];
  const float* ln2_g  = (const float*)d_in[8];
  const float* ln2_b  = (const float*)d_in[9];
  const float* mlp_w1 = (const float*)d_in[10];
  const float* mlp_b1 = (const float*)d_in[11];
  const float* mlp_w2 = (const float*)d_in[12];
  const float* mlp_b2 = (const float*)d_in[13];

  char* ws = (char*)d_ws;
  short* qkvbuf  = (short*)(ws);                 // 115.6 MB (dead after attn)
  short* hidden  = (short*)(ws);                 // [100352][768] bf16, aliases qkvbuf+obuf
  short* obuf    = (short*)(ws + 115605504);     // 38.5 MB (dead after proj_ln2)
  short* hbuf    = (short*)(ws + 154140672);     // ln1 out (dead after qkv)
  short* ln2b    = (short*)(ws + 154140672);     // ln2 out (aliases hbuf, spatial order)
  short* wT      = (short*)(ws + 192675840);
  short* qkv_wT  = wT;                            // 576*192
  short* proj_wT = wT + 110592;                   // 192*192
  short* m1_wT   = wT + 110592 + 36864;           // 768*192
  short* m2_wT   = wT + 110592 + 36864 + 147456;  // 192*768
  float* bm      = (float*)(ws + 193560576);      // [64][6][49][49] f32
  float* xout    = (float*)d_out;                 // x1 then final output

  transpose_w_k<<<(110592 + 255) / 256, 256, 0, stream>>>(qkv_w,  qkv_wT, 192, 576);
  transpose_w_k<<<(36864  + 255) / 256, 256, 0, stream>>>(proj_w, proj_wT, 192, 192);
  transpose_w_k<<<(147456 + 255) / 256, 256, 0, stream>>>(mlp_w1, m1_wT,  192, 768);
  transpose_w_k<<<(147456 + 255) / 256, 256, 0, stream>>>(mlp_w2, m2_wT,  768, 192);
  prep_bm_k<<<(64 * 6 * 2401 + 255) / 256, 256, 0, stream>>>(pos_b, bm);

  ln_k<<<25088, 256, 0, stream>>>(x, ln1_g, ln1_b, hbuf);
  pgemm_k<0><<<dim3(9, 784),  256, 0, stream>>>(hbuf, qkv_wT, qkv_b, qkvbuf, nullptr, 576, 192);
  attn_k<<<3072, 256, 0, stream>>>(qkvbuf, bm, obuf);
  proj_ln2_k<<<784, 512, 0, stream>>>(obuf, proj_wT, proj_b, x, ln2_g, ln2_b, xout, ln2b);
  pgemm_k<2><<<dim3(12, 784), 256, 0, stream>>>(ln2b, m1_wT, mlp_b1, hidden, nullptr, 768, 192);
  pgemm_k<3><<<dim3(3, 784),  256, 0, stream>>>(hidden, m2_wT, mlp_b2, xout, xout, 192, 768);
}